// Round 3
// baseline (362.479 us; speedup 1.0000x reference)
//
#include <hip/hip_runtime.h>
#include <hip/hip_bf16.h>

// LSTM B=8192,T=512,I=3,H=25 + linear[H->1], bf16 MFMA 16x16x32.
// R15: ONE WAVE = ONE CHAIN, ZERO BARRIERS. R12-R14 post-mortem: every
// multi-wave variant costs 460-555 cy/step because each recurrence step pays
// a 7-wave __syncthreads (fixed ~150+cy arrive/release/drain) - the barrier
// is the invariant cost, not the chain around it. Here a single wave64 owns
// an entire 16-batch chain:
//  - 7 register A-frags (112x32 padded gate matrix, unit-major rows);
//    7 back-to-back MFMAs per step share ONE B-frag
//  - C-layout gives lane (q,n) all 4 gates of units u=4m+q -> acts lane-local
//  - h redistribution = 7 ds_write_b16 + 1 linear ds_read_b128 SAME WAVE:
//    LDS ops of one wave complete in order -> no s_barrier anywhere
//  - x via per-lane global prefetch (3xfloat4 per 4 steps, reg ping-pong),
//    inserted into B-frag k=0..3 by register select (no LDS staging)
//  - -K1/-K2 activation prescale folded into A rows (free)
//  - 512 single-wave blocks -> 2 waves/CU on separate SIMDs, independent
// Kept: pad-slot trick (units 25..27 -> k=29..31, A cols zero), parity
// double-buffer, same activation math/clamps as the passing R12 kernel.

#define TSTEPS 512
#define ISZ 3
#define HSZ 25
#define NF 7            // fragments = units per lane

typedef __attribute__((ext_vector_type(8))) short bf16x8;
typedef __attribute__((ext_vector_type(4))) float f32x4;
typedef __attribute__((ext_vector_type(4))) int i32x4;

__device__ __forceinline__ unsigned short bf16_bits(float v) {
    return __builtin_bit_cast(unsigned short, __float2bfloat16(v));
}
__device__ __forceinline__ unsigned int pack_bf16(float lo, float hi) {
    return ((unsigned int)bf16_bits(hi) << 16) | (unsigned int)bf16_bits(lo);
}

__global__ __launch_bounds__(64) void lstm_wave(
    const float* __restrict__ x,      // [B, T, I]
    const float* __restrict__ w_ih,   // [4H, I]
    const float* __restrict__ w_hh,   // [4H, H]
    const float* __restrict__ b_ih,   // [4H]
    const float* __restrict__ b_hh,   // [4H]
    const float* __restrict__ w_lin,  // [1, H]
    const float* __restrict__ b_lin,  // [1]
    float* __restrict__ out)          // [B, 1]
{
    __shared__ short hb[2][512];      // parity-buffered B-frag, frag-linear

    const int lane = threadIdx.x;     // single wave
    const int n = lane & 15;          // batch col
    const int q = lane >> 4;          // quad
    const int b0 = blockIdx.x * 16;

    const float K1 = 1.442695040888963f;   // log2 e
    const float K2 = 2.885390081777927f;   // 2 log2 e

    // zero both parity buffers (h(0)=0); 2048 B = 64 lanes x 32 B
    ((int4*)hb)[lane]      = (int4){0, 0, 0, 0};
    ((int4*)hb)[64 + lane] = (int4){0, 0, 0, 0};

    // ---- register A fragments, activation prescale folded into rows ----
    // A[r=16m+n][k=q*8+j]; row r=4u+g unit-major; k: [w_ih 0..2, bias 3,
    // w_hh 4..28, pad 29..31]. Rows scaled by -K1 (i,f,o) / -K2 (g).
    bf16x8 afrag[NF];
    #pragma unroll
    for (int m = 0; m < NF; ++m) {
        #pragma unroll
        for (int j = 0; j < 8; ++j) {
            const int k = q * 8 + j;
            const int r = 16 * m + n;
            const int uu = r >> 2, g = r & 3;
            float v = 0.0f;
            if (uu < HSZ) {
                const int orow = g * HSZ + uu;         // original i,f,g,o order
                if (k < ISZ)            v = w_ih[orow * ISZ + k];
                else if (k == ISZ)      v = b_ih[orow] + b_hh[orow];
                else if (k < 4 + HSZ)   v = w_hh[orow * HSZ + (k - 4)];
                v *= (g == 2) ? -K2 : -K1;
            }
            afrag[m][j] = (short)bf16_bits(v);
        }
    }

    float cst[NF], hst[NF];
    #pragma unroll
    for (int m = 0; m < NF; ++m) { cst[m] = 0.f; hst[m] = 0.f; }

    const int rdoff = lane * 8;       // shorts: B-frag linear (lane*16 B)
    int woff[NF];                     // unit u=4m+q -> k-slot u+4 dest index
    #pragma unroll
    for (int m = 0; m < NF; ++m) {
        const int kw = 4 * m + q + 4;                  // <= 31 (pad ok)
        woff[m] = (kw >> 3) * 128 + n * 8 + (kw & 7);
    }

    // ---- x prefetch: 3 x float4 per 4-step group, reg ping-pong ----
    const float* __restrict__ xg = x + (size_t)(b0 + n) * (TSTEPS * ISZ);
    float4 xc0 = ((const float4*)xg)[0];
    float4 xc1 = ((const float4*)xg)[1];
    float4 xc2 = ((const float4*)xg)[2];
    float4 xn0, xn1, xn2;

    __builtin_amdgcn_wave_barrier();

    auto step = [&](int rp, float x0, float x1, float x2) {
        const int wp = rp ^ 1;
        // linear ds_read_b128 (conflict-free), then insert x on q==0 lanes
        bf16x8 frag = *(const bf16x8*)&hb[rp][rdoff];
        i32x4 fi = __builtin_bit_cast(i32x4, frag);
        const int px0 = (int)pack_bf16(x0, x1);
        const int px1 = (int)pack_bf16(x2, 1.0f);
        fi[0] = (q == 0) ? px0 : fi[0];
        fi[1] = (q == 0) ? px1 : fi[1];
        frag = __builtin_bit_cast(bf16x8, fi);

        f32x4 acc[NF];
        #pragma unroll
        for (int m = 0; m < NF; ++m)
            acc[m] = __builtin_amdgcn_mfma_f32_16x16x32_bf16(
                afrag[m], frag, (f32x4){0.f, 0.f, 0.f, 0.f}, 0, 0, 0);

        // acts: acc already -K1/-K2 prescaled; same math/clamps as R12
        #pragma unroll
        for (int m = 0; m < NF; ++m) {
            const float e0 = __builtin_amdgcn_exp2f(acc[m][0]);
            const float e1 = __builtin_amdgcn_exp2f(acc[m][1]);
            const float e2 = __builtin_amdgcn_exp2f(fminf(acc[m][2], 126.0f));
            const float e3 = __builtin_amdgcn_exp2f(acc[m][3]);
            const float f  = __builtin_amdgcn_rcpf(1.0f + e1);
            const float ig = (1.0f - e2) *
                __builtin_amdgcn_rcpf((1.0f + e0) * (1.0f + e2));
            cst[m] = fmaf(f, cst[m], ig);
            const float ec = __builtin_amdgcn_exp2f(fminf(-K2 * cst[m], 126.0f));
            hst[m] = (1.0f - ec) *
                __builtin_amdgcn_rcpf((1.0f + e3) * (1.0f + ec));
            hb[wp][woff[m]] = (short)bf16_bits(hst[m]);   // pad-slot trick
        }
        // same-wave DS ops complete in order; fence compiler reordering only
        __builtin_amdgcn_wave_barrier();
    };

    #pragma unroll 1
    for (int g = 0; g < 128; g += 2) {
        // load group g+1 while computing group g
        const float* __restrict__ p1 =
            xg + (size_t)((g + 1 < 128 ? g + 1 : 127) * 12);
        xn0 = ((const float4*)p1)[0];
        xn1 = ((const float4*)p1)[1];
        xn2 = ((const float4*)p1)[2];
        step(0, xc0.x, xc0.y, xc0.z);
        step(1, xc0.w, xc1.x, xc1.y);
        step(0, xc1.z, xc1.w, xc2.x);
        step(1, xc2.y, xc2.z, xc2.w);
        // load group g+2 while computing group g+1
        const float* __restrict__ p2 =
            xg + (size_t)((g + 2 < 128 ? g + 2 : 127) * 12);
        xc0 = ((const float4*)p2)[0];
        xc1 = ((const float4*)p2)[1];
        xc2 = ((const float4*)p2)[2];
        step(0, xn0.x, xn0.y, xn0.z);
        step(1, xn0.w, xn1.x, xn1.y);
        step(0, xn1.z, xn1.w, xn2.x);
        step(1, xn2.y, xn2.z, xn2.w);
    }

    // ---- final linear: out[b] = sum_u w_lin[u]*h[u] + b_lin ----
    float v = 0.f;
    #pragma unroll
    for (int m = 0; m < NF; ++m) {
        const int u = 4 * m + q;
        if (u < HSZ) v = fmaf(w_lin[u], hst[m], v);
    }
    v += __shfl_xor(v, 16);
    v += __shfl_xor(v, 32);
    if (q == 0) out[b0 + n] = v + b_lin[0];
}

extern "C" void kernel_launch(void* const* d_in, const int* in_sizes, int n_in,
                              void* d_out, int out_size, void* d_ws, size_t ws_size,
                              hipStream_t stream) {
    const float* x     = (const float*)d_in[0];
    const float* w_ih  = (const float*)d_in[1];
    const float* w_hh  = (const float*)d_in[2];
    const float* b_ih  = (const float*)d_in[3];
    const float* b_hh  = (const float*)d_in[4];
    const float* w_lin = (const float*)d_in[5];
    const float* b_lin = (const float*)d_in[6];
    float* out = (float*)d_out;

    lstm_wave<<<8192 / 16, 64, 0, stream>>>(x, w_ih, w_hh, b_ih, b_hh,
                                            w_lin, b_lin, out);
}